// Round 5
// baseline (105.315 us; speedup 1.0000x reference)
//
#include <hip/hip_runtime.h>
#include <hip/hip_bf16.h>

// Sizes (fixed by the reference)
#define BATCH 2
#define SEQ   4096
#define DIM   256
#define HEADS 8
#define HDIM  32
#define M_ROWS (BATCH * SEQ)   // 8192
#define JCHUNK 32
#define NCHUNK (SEQ / JCHUNK)  // 128 chunks per batch
#define CTXBLKS (BATCH * NCHUNK) // 256

typedef short bf16x8 __attribute__((ext_vector_type(8)));
typedef unsigned short u16x8 __attribute__((ext_vector_type(8)));
typedef float f32x4 __attribute__((ext_vector_type(4)));

static __device__ inline unsigned short f2bf(float x) {
  union { float f; unsigned u; } v; v.f = x;
  unsigned r = v.u + 0x7FFF + ((v.u >> 16) & 1);   // round-nearest-even
  return (unsigned short)(r >> 16);
}

// ---------------------------------------------------------------------------
// K0: prep — Wt[n][k] = bf16(Wcat[k][n]); also zeroes the ctx counter.
// ---------------------------------------------------------------------------
__global__ __launch_bounds__(256) void k_prep(const float* __restrict__ Wl,
                                              const float* __restrict__ Wr,
                                              unsigned short* __restrict__ Wt,
                                              unsigned* __restrict__ ctr) {
  if (blockIdx.x == 0 && blockIdx.y == 0 && threadIdx.x == 0) *ctr = 0u;
  __shared__ float tile[32][33];
  const int k0 = blockIdx.x * 32;
  const int n0 = blockIdx.y * 32;
  const int t = threadIdx.x;
  const float* W = (n0 < 256) ? Wl : Wr;
  const int nb = n0 & 255;
  {
    const int r = t >> 3;            // k-local
    const int c = (t & 7) * 4;       // n-local
    const float4 v = *(const float4*)(&W[(size_t)(k0 + r) * DIM + nb + c]);
    tile[r][c + 0] = v.x; tile[r][c + 1] = v.y;
    tile[r][c + 2] = v.z; tile[r][c + 3] = v.w;
  }
  __syncthreads();
  {
    const int nl = t >> 3;           // n-local
    const int kl = (t & 7) * 4;      // k-local
    ushort4 o;
    o.x = f2bf(tile[kl + 0][nl]); o.y = f2bf(tile[kl + 1][nl]);
    o.z = f2bf(tile[kl + 2][nl]); o.w = f2bf(tile[kl + 3][nl]);
    *(ushort4*)(&Wt[(size_t)(n0 + nl) * DIM + k0 + kl]) = o;
  }
}

// ---------------------------------------------------------------------------
// K1: fused MFMA GEMM + head-score epilogue (proven in R4, unchanged).
// Block (bm, isR): 64 rows x 256 cols of (isR ? fr : fl); 8 waves = 8 heads.
// fl never hits global: only msl needs it (computed here).
// ---------------------------------------------------------------------------
__global__ __launch_bounds__(512) void k_gemm_fused(
    const float* __restrict__ A, const unsigned short* __restrict__ Wt,
    const float* __restrict__ a_l, const float* __restrict__ a_r,
    float* __restrict__ fr, float* __restrict__ sr,
    float* __restrict__ msl, float* __restrict__ msr) {
  __shared__ unsigned short As[64 * 32];    // 4 KB
  __shared__ unsigned short Bs[256 * 32];   // 16 KB
  __shared__ float red[64][8];              // per-row per-head sums

  const int bid = blockIdx.x;
  const int isR = bid & 1;
  const int bm  = bid >> 1;       // 128 row tiles of 64
  const int m0 = bm * 64;
  const int n0 = isR * 256;       // Wt row offset (0: W_l, 256: W_r)

  const int t = threadIdx.x;
  const int lane = t & 63;
  const int wid = t >> 6;         // wave = head 0..7 (cols wid*32..+32)

  f32x4 acc[4][2];
  #pragma unroll
  for (int i = 0; i < 4; ++i)
    #pragma unroll
    for (int j = 0; j < 2; ++j) acc[i][j] = (f32x4){0.f, 0.f, 0.f, 0.f};

  for (int k0 = 0; k0 < DIM; k0 += 32) {
    if (t < 256) {
      const int row = t >> 2;
      const int kc = t & 3;
      const int slot = kc ^ ((row >> 1) & 3);
      const float4 a0 = *(const float4*)(&A[(size_t)(m0 + row) * DIM + k0 + kc * 8]);
      const float4 a1 = *(const float4*)(&A[(size_t)(m0 + row) * DIM + k0 + kc * 8 + 4]);
      u16x8 pa;
      pa[0] = f2bf(a0.x); pa[1] = f2bf(a0.y); pa[2] = f2bf(a0.z); pa[3] = f2bf(a0.w);
      pa[4] = f2bf(a1.x); pa[5] = f2bf(a1.y); pa[6] = f2bf(a1.z); pa[7] = f2bf(a1.w);
      *(u16x8*)((char*)As + row * 64 + slot * 16) = pa;
    }
    #pragma unroll
    for (int p = 0; p < 2; ++p) {
      const int task = t + p * 512;
      const int row = task >> 2;      // 0..255
      const int kc = task & 3;
      const int slot = kc ^ ((row >> 1) & 3);
      const u16x8 pb = *(const u16x8*)(&Wt[(size_t)(n0 + row) * DIM + k0 + kc * 8]);
      *(u16x8*)((char*)Bs + row * 64 + slot * 16) = pb;
    }
    __syncthreads();

    bf16x8 af[4], bfr[2];
    #pragma unroll
    for (int mr = 0; mr < 4; ++mr) {
      const int ra = mr * 16 + (lane & 15);
      const int sl = (lane >> 4) ^ ((ra >> 1) & 3);
      af[mr] = *(const bf16x8*)((const char*)As + ra * 64 + sl * 16);
    }
    #pragma unroll
    for (int nr = 0; nr < 2; ++nr) {
      const int cb = wid * 32 + nr * 16 + (lane & 15);
      const int sl = (lane >> 4) ^ ((cb >> 1) & 3);
      bfr[nr] = *(const bf16x8*)((const char*)Bs + cb * 64 + sl * 16);
    }
    #pragma unroll
    for (int mr = 0; mr < 4; ++mr)
      #pragma unroll
      for (int nr = 0; nr < 2; ++nr)
        acc[mr][nr] = __builtin_amdgcn_mfma_f32_16x16x32_bf16(af[mr], bfr[nr], acc[mr][nr], 0, 0, 0);
    __syncthreads();
  }

  // epilogue: per-head score sums. C/D: col=lane&15, row=(lane>>4)*4+r.
  const float* av = isR ? a_r : a_l;
  const int b = m0 >> 12;
  const int nbase = m0 & 4095;

  #pragma unroll
  for (int mr = 0; mr < 4; ++mr) {
    #pragma unroll
    for (int r = 0; r < 4; ++r) {
      float p = 0.f;
      #pragma unroll
      for (int nr = 0; nr < 2; ++nr) {
        float x = acc[mr][nr][r];
        x = x >= 0.f ? x : 0.01f * x;
        p = fmaf(x, av[nr * 16 + (lane & 15)], p);
      }
      #pragma unroll
      for (int o = 1; o < 16; o <<= 1) p += __shfl_xor(p, o, 16);
      if ((lane & 15) == 0) {
        const int rl = mr * 16 + (lane >> 4) * 4 + r;
        red[rl][wid] = p;
        if (isR) sr[((size_t)(b * HEADS + wid)) * SEQ + nbase + rl] = p;
      }
    }
  }
  __syncthreads();
  if (t < 64) {
    float s = 0.f;
    #pragma unroll
    for (int h2 = 0; h2 < 8; ++h2) s += red[t][h2];
    (isR ? msr : msl)[m0 + t] = s * 0.125f;
  }
  if (isR) {
    #pragma unroll
    for (int mr = 0; mr < 4; ++mr)
      #pragma unroll
      for (int nr = 0; nr < 2; ++nr) {
        const int col = wid * 32 + nr * 16 + (lane & 15);
        #pragma unroll
        for (int r = 0; r < 4; ++r) {
          const int row = m0 + mr * 16 + (lane >> 4) * 4 + r;
          fr[(size_t)row * DIM + col] = acc[mr][nr][r];
        }
      }
  }
}

// ---------------------------------------------------------------------------
// K2: MEGA. Blocks [0,256): ctx partials (+ last block computes fh2).
//     Blocks [256,8448): attn rows (nontemporal streaming).
// ctx: w_hj = exp(sr) unshifted (scores bounded ~±1.5); cpart coalesced.
// Last ctx block (atomic counter): reduce cpart/wpart -> c, matvec Wf -> fh2.
// Deterministic: single block, fixed order; counter zeroed in k_prep.
// ---------------------------------------------------------------------------
__global__ __launch_bounds__(256) void k_mega(const float* __restrict__ sr,
                                              const float* __restrict__ fr,
                                              const float* __restrict__ Wf,
                                              const float* __restrict__ msl,
                                              const float* __restrict__ msr,
                                              float* __restrict__ cpart,
                                              float* __restrict__ wpart,
                                              float* __restrict__ fh2,
                                              float* __restrict__ attn,
                                              unsigned* __restrict__ ctr) {
  const int blk = blockIdx.x;
  const int t = threadIdx.x;
  __shared__ float ws_[HEADS][JCHUNK];
  __shared__ float wred[HEADS];
  __shared__ float c_s[DIM];
  __shared__ unsigned done_s;

  if (blk < CTXBLKS) {
    const int b  = blk >> 7;
    const int jc = blk & 127;
    const int j0 = jc * JCHUNK;
    {
      const int h2 = t >> 5, jj = t & 31;
      float e = expf(sr[((size_t)(b * HEADS + h2)) * SEQ + j0 + jj]);
      ws_[h2][jj] = e;
      float s = e;
      #pragma unroll
      for (int o = 16; o > 0; o >>= 1) s += __shfl_xor(s, o, 32);
      if (jj == 0) wpart[(size_t)(b * NCHUNK + jc) * HEADS + h2] = s;
    }
    __syncthreads();
    {
      const int h2 = t >> 5;
      const float* frb = fr + (size_t)(b * SEQ + j0) * DIM + t;
      float accv = 0.f;
      #pragma unroll 8
      for (int jj = 0; jj < JCHUNK; ++jj)
        accv = fmaf(ws_[h2][jj], frb[(size_t)jj * DIM], accv);
      cpart[(size_t)(b * NCHUNK + jc) * DIM + t] = accv;
    }
    // last-block-done: the 256th block to finish computes fh2 for both batches
    __threadfence();
    if (t == 0) done_s = atomicAdd(ctr, 1u);
    __syncthreads();
    if (done_s == CTXBLKS - 1) {
      __threadfence();
      for (int b2 = 0; b2 < BATCH; ++b2) {
        if (t < HEADS) {
          float s = 0.f;
          for (int jc2 = 0; jc2 < NCHUNK; ++jc2)
            s += wpart[(size_t)(b2 * NCHUNK + jc2) * HEADS + t];
          wred[t] = s;
        }
        float c = 0.f;
        for (int jc2 = 0; jc2 < NCHUNK; ++jc2)
          c += cpart[(size_t)(b2 * NCHUNK + jc2) * DIM + t];
        __syncthreads();
        c_s[t] = c / wred[t >> 5];
        __syncthreads();
        float a2 = 0.f;
        #pragma unroll 8
        for (int k = 0; k < DIM; ++k)
          a2 = fmaf(c_s[k], Wf[(size_t)k * DIM + t], a2);
        fh2[b2 * DIM + t] = a2;
        __syncthreads();
      }
    }
  } else {
    // attn row: attn[b,i,j] = msl[b,i] + msr[b,j], streaming stores
    const int row = blk - CTXBLKS;       // b*4096 + i
    const int b = row >> 12;
    const float v = msl[row];
    const f32x4* mr4 = (const f32x4*)(msr + ((size_t)b << 12));
    f32x4* dst = (f32x4*)(attn + ((size_t)row << 12));
    #pragma unroll
    for (int q = 0; q < 4; ++q) {
      f32x4 m4 = mr4[q * 256 + t];
      __builtin_nontemporal_store(m4 + v, &dst[q * 256 + t]);
    }
  }
}

// ---------------------------------------------------------------------------
// K3: LayerNorm(h + fh2[b]) -> out. One block per row.
// ---------------------------------------------------------------------------
__global__ __launch_bounds__(256) void k_ln(const float* __restrict__ h,
                                            const float* __restrict__ fh2,
                                            const float* __restrict__ g,
                                            const float* __restrict__ bb,
                                            float* __restrict__ out) {
  const int row = blockIdx.x;
  const int b = row >> 12;
  const int t = threadIdx.x;
  const float x = h[(size_t)row * DIM + t] + fh2[b * DIM + t];
  float s1 = x, s2 = x * x;
  #pragma unroll
  for (int o = 32; o > 0; o >>= 1) {
    s1 += __shfl_xor(s1, o, 64);
    s2 += __shfl_xor(s2, o, 64);
  }
  __shared__ float r1[4], r2[4];
  if ((t & 63) == 0) { r1[t >> 6] = s1; r2[t >> 6] = s2; }
  __syncthreads();
  s1 = r1[0] + r1[1] + r1[2] + r1[3];
  s2 = r2[0] + r2[1] + r2[2] + r2[3];
  const float mu = s1 * (1.f / 256.f);
  const float var = s2 * (1.f / 256.f) - mu * mu;
  const float rs = rsqrtf(var + 1e-5f);
  out[(size_t)row * DIM + t] = (x - mu) * rs * g[t] + bb[t];
}

// ---------------------------------------------------------------------------
extern "C" void kernel_launch(void* const* d_in, const int* in_sizes, int n_in,
                              void* d_out, int out_size, void* d_ws, size_t ws_size,
                              hipStream_t stream) {
  const float* h  = (const float*)d_in[0];
  const float* Wl = (const float*)d_in[1];
  const float* Wr = (const float*)d_in[2];
  const float* al = (const float*)d_in[3];
  const float* ar = (const float*)d_in[4];
  const float* Wf = (const float*)d_in[5];
  const float* g  = (const float*)d_in[6];
  const float* bb = (const float*)d_in[7];
  float* out = (float*)d_out;
  float* ws  = (float*)d_ws;

  float* fr    = ws;                                 // 2,097,152 f32
  float* srs   = fr + (size_t)M_ROWS * DIM;          // 65,536
  float* msl   = srs + BATCH * HEADS * SEQ;          // 8,192
  float* msr   = msl + M_ROWS;                       // 8,192
  float* cpart = msr + M_ROWS;                       // 65,536
  float* wpart = cpart + BATCH * NCHUNK * DIM;       // 2,048
  float* fh2   = wpart + BATCH * NCHUNK * HEADS;     // 512
  unsigned short* Wt = (unsigned short*)(fh2 + BATCH * DIM); // 512*256 u16
  unsigned* ctr = (unsigned*)(Wt + 512 * DIM);

  k_prep<<<dim3(8, 16), 256, 0, stream>>>(Wl, Wr, Wt, ctr);
  k_gemm_fused<<<256, 512, 0, stream>>>(h, Wt, al, ar, fr, srs, msl, msr);
  k_mega<<<CTXBLKS + M_ROWS, 256, 0, stream>>>(srs, fr, Wf, msl, msr,
                                               cpart, wpart, fh2,
                                               out + (size_t)M_ROWS * DIM, ctr);
  k_ln<<<M_ROWS, 256, 0, stream>>>(h, fh2, g, bb, out);
}

// Round 6
// 68.534 us; speedup vs baseline: 1.5367x; 1.5367x over previous
//
#include <hip/hip_runtime.h>
#include <hip/hip_bf16.h>

// Sizes (fixed by the reference)
#define BATCH 2
#define SEQ   4096
#define DIM   256
#define HEADS 8
#define HDIM  32
#define M_ROWS (BATCH * SEQ)   // 8192
#define JCHUNK 32
#define NCHUNK (SEQ / JCHUNK)  // 128 chunks per batch
#define CTXBLKS (BATCH * NCHUNK) // 256
#define FPSCALE 4294967296.0   // 2^32 fixed-point scale

typedef short bf16x8 __attribute__((ext_vector_type(8)));
typedef unsigned short u16x8 __attribute__((ext_vector_type(8)));
typedef float f32x4 __attribute__((ext_vector_type(4)));

static __device__ inline unsigned short f2bf(float x) {
  union { float f; unsigned u; } v; v.f = x;
  unsigned r = v.u + 0x7FFF + ((v.u >> 16) & 1);   // round-nearest-even
  return (unsigned short)(r >> 16);
}

// ---------------------------------------------------------------------------
// K0: prep — Wt[n][k] = bf16(Wcat[k][n]); blocks with y==0 also zero the
// integer accumulators (re-zeroed every launch -> graph-replay safe).
// ---------------------------------------------------------------------------
__global__ __launch_bounds__(256) void k_prep(const float* __restrict__ Wl,
                                              const float* __restrict__ Wr,
                                              unsigned short* __restrict__ Wt,
                                              unsigned long long* __restrict__ yacc,
                                              unsigned long long* __restrict__ wacc) {
  if (blockIdx.y == 0) {
    const int idx = blockIdx.x * 256 + threadIdx.x;   // [0, 2048)
    yacc[2 * idx] = 0ull;
    yacc[2 * idx + 1] = 0ull;
    if (idx < BATCH * HEADS) wacc[idx] = 0ull;
  }
  __shared__ float tile[32][33];
  const int k0 = blockIdx.x * 32;
  const int n0 = blockIdx.y * 32;
  const int t = threadIdx.x;
  const float* W = (n0 < 256) ? Wl : Wr;
  const int nb = n0 & 255;
  {
    const int r = t >> 3;            // k-local
    const int c = (t & 7) * 4;       // n-local
    const float4 v = *(const float4*)(&W[(size_t)(k0 + r) * DIM + nb + c]);
    tile[r][c + 0] = v.x; tile[r][c + 1] = v.y;
    tile[r][c + 2] = v.z; tile[r][c + 3] = v.w;
  }
  __syncthreads();
  {
    const int nl = t >> 3;           // n-local
    const int kl = (t & 7) * 4;      // k-local
    ushort4 o;
    o.x = f2bf(tile[kl + 0][nl]); o.y = f2bf(tile[kl + 1][nl]);
    o.z = f2bf(tile[kl + 2][nl]); o.w = f2bf(tile[kl + 3][nl]);
    *(ushort4*)(&Wt[(size_t)(n0 + nl) * DIM + k0 + kl]) = o;
  }
}

// ---------------------------------------------------------------------------
// K1: fused MFMA GEMM + head-score epilogue (proven R4, unchanged).
// Block (bm, isR): 64 rows x 256 cols of (isR ? fr : fl); 8 waves = 8 heads.
// fl never hits global: only msl needs it (computed here).
// ---------------------------------------------------------------------------
__global__ __launch_bounds__(512) void k_gemm_fused(
    const float* __restrict__ A, const unsigned short* __restrict__ Wt,
    const float* __restrict__ a_l, const float* __restrict__ a_r,
    float* __restrict__ fr, float* __restrict__ sr,
    float* __restrict__ msl, float* __restrict__ msr) {
  __shared__ unsigned short As[64 * 32];    // 4 KB
  __shared__ unsigned short Bs[256 * 32];   // 16 KB
  __shared__ float red[64][8];              // per-row per-head sums

  const int bid = blockIdx.x;
  const int isR = bid & 1;
  const int bm  = bid >> 1;       // 128 row tiles of 64
  const int m0 = bm * 64;
  const int n0 = isR * 256;       // Wt row offset (0: W_l, 256: W_r)

  const int t = threadIdx.x;
  const int lane = t & 63;
  const int wid = t >> 6;         // wave = head 0..7 (cols wid*32..+32)

  f32x4 acc[4][2];
  #pragma unroll
  for (int i = 0; i < 4; ++i)
    #pragma unroll
    for (int j = 0; j < 2; ++j) acc[i][j] = (f32x4){0.f, 0.f, 0.f, 0.f};

  for (int k0 = 0; k0 < DIM; k0 += 32) {
    if (t < 256) {
      const int row = t >> 2;
      const int kc = t & 3;
      const int slot = kc ^ ((row >> 1) & 3);
      const float4 a0 = *(const float4*)(&A[(size_t)(m0 + row) * DIM + k0 + kc * 8]);
      const float4 a1 = *(const float4*)(&A[(size_t)(m0 + row) * DIM + k0 + kc * 8 + 4]);
      u16x8 pa;
      pa[0] = f2bf(a0.x); pa[1] = f2bf(a0.y); pa[2] = f2bf(a0.z); pa[3] = f2bf(a0.w);
      pa[4] = f2bf(a1.x); pa[5] = f2bf(a1.y); pa[6] = f2bf(a1.z); pa[7] = f2bf(a1.w);
      *(u16x8*)((char*)As + row * 64 + slot * 16) = pa;
    }
    #pragma unroll
    for (int p = 0; p < 2; ++p) {
      const int task = t + p * 512;
      const int row = task >> 2;      // 0..255
      const int kc = task & 3;
      const int slot = kc ^ ((row >> 1) & 3);
      const u16x8 pb = *(const u16x8*)(&Wt[(size_t)(n0 + row) * DIM + k0 + kc * 8]);
      *(u16x8*)((char*)Bs + row * 64 + slot * 16) = pb;
    }
    __syncthreads();

    bf16x8 af[4], bfr[2];
    #pragma unroll
    for (int mr = 0; mr < 4; ++mr) {
      const int ra = mr * 16 + (lane & 15);
      const int sl = (lane >> 4) ^ ((ra >> 1) & 3);
      af[mr] = *(const bf16x8*)((const char*)As + ra * 64 + sl * 16);
    }
    #pragma unroll
    for (int nr = 0; nr < 2; ++nr) {
      const int cb = wid * 32 + nr * 16 + (lane & 15);
      const int sl = (lane >> 4) ^ ((cb >> 1) & 3);
      bfr[nr] = *(const bf16x8*)((const char*)Bs + cb * 64 + sl * 16);
    }
    #pragma unroll
    for (int mr = 0; mr < 4; ++mr)
      #pragma unroll
      for (int nr = 0; nr < 2; ++nr)
        acc[mr][nr] = __builtin_amdgcn_mfma_f32_16x16x32_bf16(af[mr], bfr[nr], acc[mr][nr], 0, 0, 0);
    __syncthreads();
  }

  // epilogue: per-head score sums. C/D: col=lane&15, row=(lane>>4)*4+r.
  const float* av = isR ? a_r : a_l;
  const int b = m0 >> 12;
  const int nbase = m0 & 4095;

  #pragma unroll
  for (int mr = 0; mr < 4; ++mr) {
    #pragma unroll
    for (int r = 0; r < 4; ++r) {
      float p = 0.f;
      #pragma unroll
      for (int nr = 0; nr < 2; ++nr) {
        float x = acc[mr][nr][r];
        x = x >= 0.f ? x : 0.01f * x;
        p = fmaf(x, av[nr * 16 + (lane & 15)], p);
      }
      #pragma unroll
      for (int o = 1; o < 16; o <<= 1) p += __shfl_xor(p, o, 16);
      if ((lane & 15) == 0) {
        const int rl = mr * 16 + (lane >> 4) * 4 + r;
        red[rl][wid] = p;
        if (isR) sr[((size_t)(b * HEADS + wid)) * SEQ + nbase + rl] = p;
      }
    }
  }
  __syncthreads();
  if (t < 64) {
    float s = 0.f;
    #pragma unroll
    for (int h2 = 0; h2 < 8; ++h2) s += red[t][h2];
    (isR ? msr : msl)[m0 + t] = s * 0.125f;
  }
  if (isR) {
    #pragma unroll
    for (int mr = 0; mr < 4; ++mr)
      #pragma unroll
      for (int nr = 0; nr < 2; ++nr) {
        const int col = wid * 32 + nr * 16 + (lane & 15);
        #pragma unroll
        for (int r = 0; r < 4; ++r) {
          const int row = m0 + mr * 16 + (lane >> 4) * 4 + r;
          fr[(size_t)row * DIM + col] = acc[mr][nr][r];
        }
      }
  }
}

// ---------------------------------------------------------------------------
// K2: MEGA (no fences, no spin). Blocks [0,256): ctx chunk -> integer-atomic
// partial-fh accumulation (exact i64 fixed-point = deterministic).
// Blocks [256, 256+4096): attn row-pairs, nontemporal streaming stores.
// y_jc,h = (sum_jj exp(s)*fr)_h @ Wf_hblock is linear in the chunk sum, so
// per-chunk matvec + atomic add == reduce-then-matvec.
// ---------------------------------------------------------------------------
__global__ __launch_bounds__(256) void k_mega(const float* __restrict__ sr,
                                              const float* __restrict__ fr,
                                              const float* __restrict__ Wf,
                                              const float* __restrict__ msl,
                                              const float* __restrict__ msr,
                                              unsigned long long* __restrict__ yacc,
                                              unsigned long long* __restrict__ wacc,
                                              float* __restrict__ attn) {
  const int blk = blockIdx.x;
  const int t = threadIdx.x;

  if (blk < CTXBLKS) {
    __shared__ float ws_[HEADS][JCHUNK];
    __shared__ float cps[DIM];
    const int b  = blk >> 7;
    const int jc = blk & 127;
    const int j0 = jc * JCHUNK;
    {
      const int h2 = t >> 5, jj = t & 31;
      float e = expf(sr[((size_t)(b * HEADS + h2)) * SEQ + j0 + jj]);
      ws_[h2][jj] = e;
      float s = e;
      #pragma unroll
      for (int o = 16; o > 0; o >>= 1) s += __shfl_xor(s, o, 32);
      if (jj == 0)
        atomicAdd(&wacc[b * HEADS + h2],
                  (unsigned long long)__double2ll_rn((double)s * FPSCALE));
    }
    __syncthreads();
    {
      const int h2 = t >> 5;
      const float* frb = fr + (size_t)(b * SEQ + j0) * DIM + t;
      float accv = 0.f;
      #pragma unroll 8
      for (int jj = 0; jj < JCHUNK; ++jj)
        accv = fmaf(ws_[h2][jj], frb[(size_t)jj * DIM], accv);
      cps[t] = accv;
    }
    __syncthreads();
    // per-chunk y: for each head, 32-dim slice times Wf block, col t
    #pragma unroll
    for (int h2 = 0; h2 < HEADS; ++h2) {
      float yh = 0.f;
      #pragma unroll 8
      for (int d = 0; d < HDIM; ++d)
        yh = fmaf(cps[h2 * HDIM + d], Wf[(size_t)(h2 * HDIM + d) * DIM + t], yh);
      atomicAdd(&yacc[(size_t)(b * HEADS + h2) * DIM + t],
                (unsigned long long)__double2ll_rn((double)yh * FPSCALE));
    }
  } else {
    // attn row-pair: attn[b,i,j] = msl[b,i] + msr[b,j]
    const int pr = blk - CTXBLKS;          // [0, 4096)
    const int row0 = pr * 2;
    const int b = row0 >> 12;
    const float v0 = msl[row0];
    const float v1 = msl[row0 + 1];
    const f32x4* mr4 = (const f32x4*)(msr + ((size_t)b << 12));
    f32x4* dst0 = (f32x4*)(attn + ((size_t)row0 << 12));
    f32x4* dst1 = (f32x4*)(attn + ((size_t)(row0 + 1) << 12));
    #pragma unroll
    for (int q = 0; q < 4; ++q) {
      const f32x4 m4 = mr4[q * 256 + t];
      __builtin_nontemporal_store(m4 + v0, &dst0[q * 256 + t]);
      __builtin_nontemporal_store(m4 + v1, &dst1[q * 256 + t]);
    }
  }
}

// ---------------------------------------------------------------------------
// K3: LayerNorm(h + fh2[b]) -> out, 2 rows per block.
// fh2[b][t] = sum_h yacc[b,h,t] / wacc[b,h]  (exact i64 -> double).
// ---------------------------------------------------------------------------
__global__ __launch_bounds__(256) void k_ln(const float* __restrict__ h,
                                            const unsigned long long* __restrict__ yacc,
                                            const unsigned long long* __restrict__ wacc,
                                            const float* __restrict__ g,
                                            const float* __restrict__ bb,
                                            float* __restrict__ out) {
  const int pr = blockIdx.x;
  const int row0 = pr * 2;
  const int b = row0 >> 12;
  const int t = threadIdx.x;

  float fh = 0.f;
  #pragma unroll
  for (int h2 = 0; h2 < HEADS; ++h2) {
    const double yv = (double)(long long)yacc[(size_t)(b * HEADS + h2) * DIM + t];
    const double wv = (double)(long long)wacc[b * HEADS + h2];
    fh += (float)(yv / wv);
  }

  const float x0 = h[(size_t)row0 * DIM + t] + fh;
  const float x1 = h[(size_t)(row0 + 1) * DIM + t] + fh;
  float s10 = x0, s20 = x0 * x0, s11 = x1, s21 = x1 * x1;
  #pragma unroll
  for (int o = 32; o > 0; o >>= 1) {
    s10 += __shfl_xor(s10, o, 64);
    s20 += __shfl_xor(s20, o, 64);
    s11 += __shfl_xor(s11, o, 64);
    s21 += __shfl_xor(s21, o, 64);
  }
  __shared__ float r1[2][4], r2[2][4];
  if ((t & 63) == 0) {
    r1[0][t >> 6] = s10; r2[0][t >> 6] = s20;
    r1[1][t >> 6] = s11; r2[1][t >> 6] = s21;
  }
  __syncthreads();
  const float gs = g[t], bs = bb[t];
  {
    const float s1 = r1[0][0] + r1[0][1] + r1[0][2] + r1[0][3];
    const float s2 = r2[0][0] + r2[0][1] + r2[0][2] + r2[0][3];
    const float mu = s1 * (1.f / 256.f);
    const float var = s2 * (1.f / 256.f) - mu * mu;
    const float rs = rsqrtf(var + 1e-5f);
    out[(size_t)row0 * DIM + t] = (x0 - mu) * rs * gs + bs;
  }
  {
    const float s1 = r1[1][0] + r1[1][1] + r1[1][2] + r1[1][3];
    const float s2 = r2[1][0] + r2[1][1] + r2[1][2] + r2[1][3];
    const float mu = s1 * (1.f / 256.f);
    const float var = s2 * (1.f / 256.f) - mu * mu;
    const float rs = rsqrtf(var + 1e-5f);
    out[(size_t)(row0 + 1) * DIM + t] = (x1 - mu) * rs * gs + bs;
  }
}

// ---------------------------------------------------------------------------
extern "C" void kernel_launch(void* const* d_in, const int* in_sizes, int n_in,
                              void* d_out, int out_size, void* d_ws, size_t ws_size,
                              hipStream_t stream) {
  const float* h  = (const float*)d_in[0];
  const float* Wl = (const float*)d_in[1];
  const float* Wr = (const float*)d_in[2];
  const float* al = (const float*)d_in[3];
  const float* ar = (const float*)d_in[4];
  const float* Wf = (const float*)d_in[5];
  const float* g  = (const float*)d_in[6];
  const float* bb = (const float*)d_in[7];
  float* out = (float*)d_out;

  // i64 accumulators first (8B alignment), then f32 scratch, then bf16 Wt
  unsigned long long* yacc = (unsigned long long*)d_ws;         // 4096 i64
  unsigned long long* wacc = yacc + BATCH * HEADS * DIM;        // 16 i64
  float* fr  = (float*)(wacc + BATCH * HEADS);                  // 2,097,152 f32
  float* srs = fr + (size_t)M_ROWS * DIM;                       // 65,536
  float* msl = srs + BATCH * HEADS * SEQ;                       // 8,192
  float* msr = msl + M_ROWS;                                    // 8,192
  unsigned short* Wt = (unsigned short*)(msr + M_ROWS);         // 512*256 u16

  k_prep<<<dim3(8, 16), 256, 0, stream>>>(Wl, Wr, Wt, yacc, wacc);
  k_gemm_fused<<<256, 512, 0, stream>>>(h, Wt, al, ar, fr, srs, msl, msr);
  k_mega<<<CTXBLKS + M_ROWS / 2, 256, 0, stream>>>(srs, fr, Wf, msl, msr,
                                                   yacc, wacc,
                                                   out + (size_t)M_ROWS * DIM);
  k_ln<<<M_ROWS / 2, 256, 0, stream>>>(h, yacc, wacc, g, bb, out);
}

// Round 7
// 61.869 us; speedup vs baseline: 1.7022x; 1.1077x over previous
//
#include <hip/hip_runtime.h>
#include <hip/hip_bf16.h>

// Sizes (fixed by the reference)
#define BATCH 2
#define SEQ   4096
#define DIM   256
#define HEADS 8
#define HDIM  32
#define M_ROWS (BATCH * SEQ)   // 8192
#define JCHUNK 64
#define NCHUNK (SEQ / JCHUNK)  // 64 chunks per batch
#define CTXBLKS (BATCH * NCHUNK) // 128
#define FPSCALE 4294967296.0   // 2^32 fixed-point scale

typedef short bf16x8 __attribute__((ext_vector_type(8)));
typedef unsigned short u16x8 __attribute__((ext_vector_type(8)));
typedef float f32x4 __attribute__((ext_vector_type(4)));

static __device__ inline unsigned short f2bf(float x) {
  union { float f; unsigned u; } v; v.f = x;
  unsigned r = v.u + 0x7FFF + ((v.u >> 16) & 1);   // round-nearest-even
  return (unsigned short)(r >> 16);
}

// ---------------------------------------------------------------------------
// K0: prep — Wt[n][k] = bf16(Wcat[k][n]); y==0 blocks zero yacc/wacc
// (re-zeroed every launch -> graph-replay safe, stream-ordered).
// ---------------------------------------------------------------------------
__global__ __launch_bounds__(256) void k_prep(const float* __restrict__ Wl,
                                              const float* __restrict__ Wr,
                                              unsigned short* __restrict__ Wt,
                                              unsigned long long* __restrict__ yacc,
                                              unsigned long long* __restrict__ wacc) {
  if (blockIdx.y == 0) {
    const int idx = blockIdx.x * 256 + threadIdx.x;   // [0, 2048)
    yacc[2 * idx] = 0ull;
    yacc[2 * idx + 1] = 0ull;
    if (idx < BATCH * HEADS) wacc[idx] = 0ull;
  }
  __shared__ float tile[32][33];
  const int k0 = blockIdx.x * 32;
  const int n0 = blockIdx.y * 32;
  const int t = threadIdx.x;
  const float* W = (n0 < 256) ? Wl : Wr;
  const int nb = n0 & 255;
  {
    const int r = t >> 3;            // k-local
    const int c = (t & 7) * 4;       // n-local
    const float4 v = *(const float4*)(&W[(size_t)(k0 + r) * DIM + nb + c]);
    tile[r][c + 0] = v.x; tile[r][c + 1] = v.y;
    tile[r][c + 2] = v.z; tile[r][c + 3] = v.w;
  }
  __syncthreads();
  {
    const int nl = t >> 3;           // n-local
    const int kl = (t & 7) * 4;      // k-local
    ushort4 o;
    o.x = f2bf(tile[kl + 0][nl]); o.y = f2bf(tile[kl + 1][nl]);
    o.z = f2bf(tile[kl + 2][nl]); o.w = f2bf(tile[kl + 3][nl]);
    *(ushort4*)(&Wt[(size_t)(n0 + nl) * DIM + k0 + kl]) = o;
  }
}

// ---------------------------------------------------------------------------
// K1: fused MFMA GEMM + head-score epilogue, now DOUBLE-BUFFERED.
// 256 blocks = 1 block/CU (8 waves): no TLP to hide global latency, so
// per iter: issue next K-tile loads -> MFMA current from LDS[cur] ->
// commit regs into LDS[cur^1] -> one barrier. Hides ~600ns x 7 stalls.
// Block (bm, isR): 64 rows x 256 cols of (isR ? fr : fl); wave = head.
// fl never hits global: only msl needs it (computed here).
// ---------------------------------------------------------------------------
__global__ __launch_bounds__(512) void k_gemm_fused(
    const float* __restrict__ A, const unsigned short* __restrict__ Wt,
    const float* __restrict__ a_l, const float* __restrict__ a_r,
    float* __restrict__ fr, float* __restrict__ sr,
    float* __restrict__ msl, float* __restrict__ msr) {
  __shared__ unsigned short As2[2][64 * 32];    // 2 x 4 KB
  __shared__ unsigned short Bs2[2][256 * 32];   // 2 x 16 KB
  __shared__ float red[64][8];

  const int bid = blockIdx.x;
  const int isR = bid & 1;
  const int bm  = bid >> 1;       // 128 row tiles of 64
  const int m0 = bm * 64;
  const int n0 = isR * 256;       // Wt row offset (0: W_l, 256: W_r)

  const int t = threadIdx.x;
  const int lane = t & 63;
  const int wid = t >> 6;         // wave = head 0..7 (cols wid*32..+32)

  // staging coords
  const int arow = t >> 2;        // t<256: 0..63
  const int akc  = t & 3;
  const int aslot = akc ^ ((arow >> 1) & 3);
  const int brow = t >> 2;        // 0..127 (second task: +128, same slot)
  const int bkc  = t & 3;
  const int bslot = bkc ^ ((brow >> 1) & 3);

  float4 a0r, a1r;
  u16x8 b0r, b1r;

  // prologue: issue + commit K-tile 0
  if (t < 256) {
    a0r = *(const float4*)(&A[(size_t)(m0 + arow) * DIM + akc * 8]);
    a1r = *(const float4*)(&A[(size_t)(m0 + arow) * DIM + akc * 8 + 4]);
  }
  b0r = *(const u16x8*)(&Wt[(size_t)(n0 + brow) * DIM + bkc * 8]);
  b1r = *(const u16x8*)(&Wt[(size_t)(n0 + 128 + brow) * DIM + bkc * 8]);
  if (t < 256) {
    u16x8 pa;
    pa[0] = f2bf(a0r.x); pa[1] = f2bf(a0r.y); pa[2] = f2bf(a0r.z); pa[3] = f2bf(a0r.w);
    pa[4] = f2bf(a1r.x); pa[5] = f2bf(a1r.y); pa[6] = f2bf(a1r.z); pa[7] = f2bf(a1r.w);
    *(u16x8*)((char*)As2[0] + arow * 64 + aslot * 16) = pa;
  }
  *(u16x8*)((char*)Bs2[0] + brow * 64 + bslot * 16) = b0r;
  *(u16x8*)((char*)Bs2[0] + (128 + brow) * 64 + bslot * 16) = b1r;
  __syncthreads();

  f32x4 acc[4][2];
  #pragma unroll
  for (int i = 0; i < 4; ++i)
    #pragma unroll
    for (int j = 0; j < 2; ++j) acc[i][j] = (f32x4){0.f, 0.f, 0.f, 0.f};

  for (int ks = 0; ks < 8; ++ks) {
    const int cur = ks & 1;
    if (ks < 7) {                      // issue next tile's global loads
      const int k0 = (ks + 1) * 32;
      if (t < 256) {
        a0r = *(const float4*)(&A[(size_t)(m0 + arow) * DIM + k0 + akc * 8]);
        a1r = *(const float4*)(&A[(size_t)(m0 + arow) * DIM + k0 + akc * 8 + 4]);
      }
      b0r = *(const u16x8*)(&Wt[(size_t)(n0 + brow) * DIM + k0 + bkc * 8]);
      b1r = *(const u16x8*)(&Wt[(size_t)(n0 + 128 + brow) * DIM + k0 + bkc * 8]);
    }

    bf16x8 af[4], bfr[2];
    #pragma unroll
    for (int mr = 0; mr < 4; ++mr) {
      const int ra = mr * 16 + (lane & 15);
      const int sl = (lane >> 4) ^ ((ra >> 1) & 3);
      af[mr] = *(const bf16x8*)((const char*)As2[cur] + ra * 64 + sl * 16);
    }
    #pragma unroll
    for (int nr = 0; nr < 2; ++nr) {
      const int cb = wid * 32 + nr * 16 + (lane & 15);
      const int sl = (lane >> 4) ^ ((cb >> 1) & 3);
      bfr[nr] = *(const bf16x8*)((const char*)Bs2[cur] + cb * 64 + sl * 16);
    }
    #pragma unroll
    for (int mr = 0; mr < 4; ++mr)
      #pragma unroll
      for (int nr = 0; nr < 2; ++nr)
        acc[mr][nr] = __builtin_amdgcn_mfma_f32_16x16x32_bf16(af[mr], bfr[nr], acc[mr][nr], 0, 0, 0);

    if (ks < 7) {                      // commit next tile into other buffer
      if (t < 256) {
        u16x8 pa;
        pa[0] = f2bf(a0r.x); pa[1] = f2bf(a0r.y); pa[2] = f2bf(a0r.z); pa[3] = f2bf(a0r.w);
        pa[4] = f2bf(a1r.x); pa[5] = f2bf(a1r.y); pa[6] = f2bf(a1r.z); pa[7] = f2bf(a1r.w);
        *(u16x8*)((char*)As2[cur ^ 1] + arow * 64 + aslot * 16) = pa;
      }
      *(u16x8*)((char*)Bs2[cur ^ 1] + brow * 64 + bslot * 16) = b0r;
      *(u16x8*)((char*)Bs2[cur ^ 1] + (128 + brow) * 64 + bslot * 16) = b1r;
    }
    __syncthreads();
  }

  // epilogue: per-head score sums. C/D: col=lane&15, row=(lane>>4)*4+r.
  const float* av = isR ? a_r : a_l;
  const int b = m0 >> 12;
  const int nbase = m0 & 4095;

  #pragma unroll
  for (int mr = 0; mr < 4; ++mr) {
    #pragma unroll
    for (int r = 0; r < 4; ++r) {
      float p = 0.f;
      #pragma unroll
      for (int nr = 0; nr < 2; ++nr) {
        float x = acc[mr][nr][r];
        x = x >= 0.f ? x : 0.01f * x;
        p = fmaf(x, av[nr * 16 + (lane & 15)], p);
      }
      #pragma unroll
      for (int o = 1; o < 16; o <<= 1) p += __shfl_xor(p, o, 16);
      if ((lane & 15) == 0) {
        const int rl = mr * 16 + (lane >> 4) * 4 + r;
        red[rl][wid] = p;
        if (isR) sr[((size_t)(b * HEADS + wid)) * SEQ + nbase + rl] = p;
      }
    }
  }
  __syncthreads();
  if (t < 64) {
    float s = 0.f;
    #pragma unroll
    for (int h2 = 0; h2 < 8; ++h2) s += red[t][h2];
    (isR ? msr : msl)[m0 + t] = s * 0.125f;
  }
  if (isR) {
    #pragma unroll
    for (int mr = 0; mr < 4; ++mr)
      #pragma unroll
      for (int nr = 0; nr < 2; ++nr) {
        const int col = wid * 32 + nr * 16 + (lane & 15);
        #pragma unroll
        for (int r = 0; r < 4; ++r) {
          const int row = m0 + mr * 16 + (lane >> 4) * 4 + r;
          fr[(size_t)row * DIM + col] = acc[mr][nr][r];
        }
      }
  }
}

// ---------------------------------------------------------------------------
// K2: ctx chunk (homogeneous, 128 blocks). w = exp(sr) unshifted (|s|<~1.5).
// Per-chunk unnormalized context cps, then per-head matvec vs Wf (linearity:
// chunk-matvec + exact i64 atomic add == reduce-then-matvec). Deterministic.
// ---------------------------------------------------------------------------
__global__ __launch_bounds__(256) void k_ctx(const float* __restrict__ sr,
                                             const float* __restrict__ fr,
                                             const float* __restrict__ Wf,
                                             unsigned long long* __restrict__ yacc,
                                             unsigned long long* __restrict__ wacc) {
  const int blk = blockIdx.x;
  const int b  = blk >> 6;
  const int jc = blk & 63;
  const int j0 = jc * JCHUNK;
  const int t = threadIdx.x;
  __shared__ float ws_[HEADS][JCHUNK];   // 2 KB
  __shared__ float cps[DIM];

  {
    const int h2 = t >> 5, jj = t & 31;
    const float* sb = sr + ((size_t)(b * HEADS + h2)) * SEQ + j0;
    const float e0 = expf(sb[jj]);
    const float e1 = expf(sb[jj + 32]);
    ws_[h2][jj] = e0;
    ws_[h2][jj + 32] = e1;
    float s = e0 + e1;
    #pragma unroll
    for (int o = 16; o > 0; o >>= 1) s += __shfl_xor(s, o, 32);
    if (jj == 0)
      atomicAdd(&wacc[b * HEADS + h2],
                (unsigned long long)__double2ll_rn((double)s * FPSCALE));
  }
  __syncthreads();
  {
    const int h2 = t >> 5;
    const float* frb = fr + (size_t)(b * SEQ + j0) * DIM + t;
    float accv = 0.f;
    #pragma unroll 8
    for (int jj = 0; jj < JCHUNK; ++jj)
      accv = fmaf(ws_[h2][jj], frb[(size_t)jj * DIM], accv);
    cps[t] = accv;
  }
  __syncthreads();
  #pragma unroll
  for (int h3 = 0; h3 < HEADS; ++h3) {
    float yh = 0.f;
    #pragma unroll 8
    for (int d = 0; d < HDIM; ++d)
      yh = fmaf(cps[h3 * HDIM + d], Wf[(size_t)(h3 * HDIM + d) * DIM + t], yh);
    atomicAdd(&yacc[(size_t)(b * HEADS + h3) * DIM + t],
              (unsigned long long)__double2ll_rn((double)yh * FPSCALE));
  }
}

// ---------------------------------------------------------------------------
// K3: fused LayerNorm + attn outer-sum (R4's proven shape). One block/row.
// fh[t] = sum_h yacc[b,h,t] * (1/wacc[b,h]) — scales cancel exactly.
// ---------------------------------------------------------------------------
__global__ __launch_bounds__(256) void k_ln_attn(const float* __restrict__ h,
                                                 const unsigned long long* __restrict__ yacc,
                                                 const unsigned long long* __restrict__ wacc,
                                                 const float* __restrict__ g,
                                                 const float* __restrict__ bb,
                                                 const float* __restrict__ msl,
                                                 const float* __restrict__ msr,
                                                 float* __restrict__ out,
                                                 float* __restrict__ attn) {
  const int row = blockIdx.x;
  const int b = row >> 12;
  const int t = threadIdx.x;
  __shared__ float winv[HEADS];
  if (t < HEADS)
    winv[t] = (float)(1.0 / (double)(long long)wacc[b * HEADS + t]);
  __syncthreads();

  float fh = 0.f;
  #pragma unroll
  for (int h2 = 0; h2 < HEADS; ++h2)
    fh = fmaf((float)(long long)yacc[(size_t)(b * HEADS + h2) * DIM + t],
              winv[h2], fh);

  const float x = h[(size_t)row * DIM + t] + fh;
  float s1 = x, s2 = x * x;
  #pragma unroll
  for (int o = 32; o > 0; o >>= 1) {
    s1 += __shfl_xor(s1, o, 64);
    s2 += __shfl_xor(s2, o, 64);
  }
  __shared__ float r1[4], r2[4];
  if ((t & 63) == 0) { r1[t >> 6] = s1; r2[t >> 6] = s2; }
  __syncthreads();
  s1 = r1[0] + r1[1] + r1[2] + r1[3];
  s2 = r2[0] + r2[1] + r2[2] + r2[3];
  const float mu = s1 * (1.f / 256.f);
  const float var = s2 * (1.f / 256.f) - mu * mu;
  const float rs = rsqrtf(var + 1e-5f);
  out[(size_t)row * DIM + t] = (x - mu) * rs * g[t] + bb[t];

  // attn row: streaming non-temporal stores
  const float v = msl[row];
  const f32x4* mr4 = (const f32x4*)(msr + ((size_t)b << 12));
  f32x4* dst = (f32x4*)(attn + ((size_t)row << 12));
  #pragma unroll
  for (int q = 0; q < 4; ++q) {
    const f32x4 m4 = mr4[q * 256 + t];
    __builtin_nontemporal_store(m4 + v, &dst[q * 256 + t]);
  }
}

// ---------------------------------------------------------------------------
extern "C" void kernel_launch(void* const* d_in, const int* in_sizes, int n_in,
                              void* d_out, int out_size, void* d_ws, size_t ws_size,
                              hipStream_t stream) {
  const float* h  = (const float*)d_in[0];
  const float* Wl = (const float*)d_in[1];
  const float* Wr = (const float*)d_in[2];
  const float* al = (const float*)d_in[3];
  const float* ar = (const float*)d_in[4];
  const float* Wf = (const float*)d_in[5];
  const float* g  = (const float*)d_in[6];
  const float* bb = (const float*)d_in[7];
  float* out = (float*)d_out;

  unsigned long long* yacc = (unsigned long long*)d_ws;         // 4096 i64
  unsigned long long* wacc = yacc + BATCH * HEADS * DIM;        // 16 i64
  float* fr  = (float*)(wacc + BATCH * HEADS);                  // 2,097,152 f32
  float* srs = fr + (size_t)M_ROWS * DIM;                       // 65,536
  float* msl = srs + BATCH * HEADS * SEQ;                       // 8,192
  float* msr = msl + M_ROWS;                                    // 8,192
  unsigned short* Wt = (unsigned short*)(msr + M_ROWS);         // 512*256 u16

  k_prep<<<dim3(8, 16), 256, 0, stream>>>(Wl, Wr, Wt, yacc, wacc);
  k_gemm_fused<<<256, 512, 0, stream>>>(h, Wt, al, ar, fr, srs, msl, msr);
  k_ctx<<<CTXBLKS, 256, 0, stream>>>(srs, fr, Wf, yacc, wacc);
  k_ln_attn<<<M_ROWS, 256, 0, stream>>>(h, yacc, wacc, g, bb, msl, msr,
                                        out, out + (size_t)M_ROWS * DIM);
}

// Round 8
// 57.048 us; speedup vs baseline: 1.8461x; 1.0845x over previous
//
#include <hip/hip_runtime.h>
#include <hip/hip_bf16.h>

// Sizes (fixed by the reference)
#define BATCH 2
#define SEQ   4096
#define DIM   256
#define HEADS 8
#define HDIM  32
#define M_ROWS (BATCH * SEQ)   // 8192
#define FPSCALE 4294967296.0   // 2^32 fixed-point scale

typedef short bf16x8 __attribute__((ext_vector_type(8)));
typedef unsigned short u16x8 __attribute__((ext_vector_type(8)));
typedef float f32x4 __attribute__((ext_vector_type(4)));

static __device__ inline unsigned short f2bf(float x) {
  union { float f; unsigned u; } v; v.f = x;
  unsigned r = v.u + 0x7FFF + ((v.u >> 16) & 1);   // round-nearest-even
  return (unsigned short)(r >> 16);
}

// ---------------------------------------------------------------------------
// K0: prep — Wt[n][k] = bf16(Wcat[k][n]); y==0 blocks zero yctx/wacc
// (re-zeroed every launch -> graph-replay safe, stream-ordered).
// ---------------------------------------------------------------------------
__global__ __launch_bounds__(256) void k_prep(const float* __restrict__ Wl,
                                              const float* __restrict__ Wr,
                                              unsigned short* __restrict__ Wt,
                                              unsigned long long* __restrict__ yctx,
                                              unsigned long long* __restrict__ wacc) {
  if (blockIdx.y == 0) {
    const int idx = blockIdx.x * 256 + threadIdx.x;   // [0, 2048)
    if (idx < BATCH * DIM) yctx[idx] = 0ull;
    if (idx < BATCH * HEADS) wacc[idx] = 0ull;
  }
  __shared__ float tile[32][33];
  const int k0 = blockIdx.x * 32;
  const int n0 = blockIdx.y * 32;
  const int t = threadIdx.x;
  const float* W = (n0 < 256) ? Wl : Wr;
  const int nb = n0 & 255;
  {
    const int r = t >> 3;            // k-local
    const int c = (t & 7) * 4;       // n-local
    const float4 v = *(const float4*)(&W[(size_t)(k0 + r) * DIM + nb + c]);
    tile[r][c + 0] = v.x; tile[r][c + 1] = v.y;
    tile[r][c + 2] = v.z; tile[r][c + 3] = v.w;
  }
  __syncthreads();
  {
    const int nl = t >> 3;           // n-local
    const int kl = (t & 7) * 4;      // k-local
    ushort4 o;
    o.x = f2bf(tile[kl + 0][nl]); o.y = f2bf(tile[kl + 1][nl]);
    o.z = f2bf(tile[kl + 2][nl]); o.w = f2bf(tile[kl + 3][nl]);
    *(ushort4*)(&Wt[(size_t)(n0 + nl) * DIM + k0 + kl]) = o;
  }
}

// ---------------------------------------------------------------------------
// K1: fused MFMA GEMM + FULL score/context epilogue. R4's proven single-
// buffered core. Block (bm, isR): 64 rows x 256 cols of (isR ? fr : fl);
// wave = head. NOTHING large is written to global:
//  - msl/msr: per-row head-mean scores (64 f32 per block)
//  - isR only: e_j = exp(score) per row; block-partial context
//    y[col] = sum_rows e*C[row,col] and wsum[h] = sum_rows e, accumulated
//    via EXACT i64 fixed-point atomics (associative -> deterministic).
// fr itself is consumed in-register; never stored.
// ---------------------------------------------------------------------------
__global__ __launch_bounds__(512) void k_gemm_fused(
    const float* __restrict__ A, const unsigned short* __restrict__ Wt,
    const float* __restrict__ a_l, const float* __restrict__ a_r,
    float* __restrict__ msl, float* __restrict__ msr,
    unsigned long long* __restrict__ yctx,
    unsigned long long* __restrict__ wacc) {
  __shared__ unsigned short As[64 * 32];    // 4 KB
  __shared__ unsigned short Bs[256 * 32];   // 16 KB
  __shared__ float red[64][8];              // per-row per-head scores

  const int bid = blockIdx.x;
  const int isR = bid & 1;
  const int bm  = bid >> 1;       // 128 row tiles of 64
  const int m0 = bm * 64;
  const int n0 = isR * 256;       // Wt row offset (0: W_l, 256: W_r)

  const int t = threadIdx.x;
  const int lane = t & 63;
  const int wid = t >> 6;         // wave = head 0..7 (cols wid*32..+32)

  f32x4 acc[4][2];
  #pragma unroll
  for (int i = 0; i < 4; ++i)
    #pragma unroll
    for (int j = 0; j < 2; ++j) acc[i][j] = (f32x4){0.f, 0.f, 0.f, 0.f};

  for (int k0 = 0; k0 < DIM; k0 += 32) {
    if (t < 256) {
      const int row = t >> 2;
      const int kc = t & 3;
      const int slot = kc ^ ((row >> 1) & 3);
      const float4 a0 = *(const float4*)(&A[(size_t)(m0 + row) * DIM + k0 + kc * 8]);
      const float4 a1 = *(const float4*)(&A[(size_t)(m0 + row) * DIM + k0 + kc * 8 + 4]);
      u16x8 pa;
      pa[0] = f2bf(a0.x); pa[1] = f2bf(a0.y); pa[2] = f2bf(a0.z); pa[3] = f2bf(a0.w);
      pa[4] = f2bf(a1.x); pa[5] = f2bf(a1.y); pa[6] = f2bf(a1.z); pa[7] = f2bf(a1.w);
      *(u16x8*)((char*)As + row * 64 + slot * 16) = pa;
    }
    #pragma unroll
    for (int p = 0; p < 2; ++p) {
      const int task = t + p * 512;
      const int row = task >> 2;      // 0..255
      const int kc = task & 3;
      const int slot = kc ^ ((row >> 1) & 3);
      const u16x8 pb = *(const u16x8*)(&Wt[(size_t)(n0 + row) * DIM + k0 + kc * 8]);
      *(u16x8*)((char*)Bs + row * 64 + slot * 16) = pb;
    }
    __syncthreads();

    bf16x8 af[4], bfr[2];
    #pragma unroll
    for (int mr = 0; mr < 4; ++mr) {
      const int ra = mr * 16 + (lane & 15);
      const int sl = (lane >> 4) ^ ((ra >> 1) & 3);
      af[mr] = *(const bf16x8*)((const char*)As + ra * 64 + sl * 16);
    }
    #pragma unroll
    for (int nr = 0; nr < 2; ++nr) {
      const int cb = wid * 32 + nr * 16 + (lane & 15);
      const int sl = (lane >> 4) ^ ((cb >> 1) & 3);
      bfr[nr] = *(const bf16x8*)((const char*)Bs + cb * 64 + sl * 16);
    }
    #pragma unroll
    for (int mr = 0; mr < 4; ++mr)
      #pragma unroll
      for (int nr = 0; nr < 2; ++nr)
        acc[mr][nr] = __builtin_amdgcn_mfma_f32_16x16x32_bf16(af[mr], bfr[nr], acc[mr][nr], 0, 0, 0);
    __syncthreads();
  }

  // ---- epilogue. C/D layout: row = mr*16 + (lane>>4)*4 + r, col = lane&15.
  const float* av = isR ? a_r : a_l;
  const int b = m0 >> 12;

  float e[4][4];      // exp(score) per owned row (isR only use)
  #pragma unroll
  for (int mr = 0; mr < 4; ++mr) {
    #pragma unroll
    for (int r = 0; r < 4; ++r) {
      float p = 0.f;
      #pragma unroll
      for (int nr = 0; nr < 2; ++nr) {
        float x = acc[mr][nr][r];
        x = x >= 0.f ? x : 0.01f * x;
        p = fmaf(x, av[nr * 16 + (lane & 15)], p);
      }
      // butterfly: all 16 lanes of the col-group get the row score
      #pragma unroll
      for (int o = 1; o < 16; o <<= 1) p += __shfl_xor(p, o, 16);
      if ((lane & 15) == 0) {
        const int rl = mr * 16 + (lane >> 4) * 4 + r;
        red[rl][wid] = p;
      }
      e[mr][r] = __expf(p) ;
    }
  }

  if (isR) {
    // block-partial wsum for head wid: sum e over 64 rows
    float se = 0.f;
    #pragma unroll
    for (int mr = 0; mr < 4; ++mr)
      #pragma unroll
      for (int r = 0; r < 4; ++r) se += e[mr][r];
    se += __shfl_xor(se, 16, 64);
    se += __shfl_xor(se, 32, 64);
    if (lane == 0)
      atomicAdd(&wacc[b * HEADS + wid],
                (unsigned long long)__double2ll_rn((double)se * FPSCALE));
    // block-partial context: y[col] = sum_rows e * C[row,col] (raw, not leaky)
    #pragma unroll
    for (int nr = 0; nr < 2; ++nr) {
      float y = 0.f;
      #pragma unroll
      for (int mr = 0; mr < 4; ++mr)
        #pragma unroll
        for (int r = 0; r < 4; ++r)
          y = fmaf(e[mr][r], acc[mr][nr][r], y);
      y += __shfl_xor(y, 16, 64);
      y += __shfl_xor(y, 32, 64);
      if (lane < 16)
        atomicAdd(&yctx[(size_t)b * DIM + wid * 32 + nr * 16 + lane],
                  (unsigned long long)__double2ll_rn((double)y * FPSCALE));
    }
  }
  __syncthreads();
  if (t < 64) {
    float s = 0.f;
    #pragma unroll
    for (int h2 = 0; h2 < 8; ++h2) s += red[t][h2];
    (isR ? msr : msl)[m0 + t] = s * 0.125f;
  }
}

// ---------------------------------------------------------------------------
// K2: normalize context + matvec with W_final. 2 blocks (one per batch).
// c[d] = yctx[b,d]/wacc[b,d>>5]; fh2[b,n] = sum_d c[d]*Wf[d,n].
// ---------------------------------------------------------------------------
__global__ __launch_bounds__(256) void k_fh(const unsigned long long* __restrict__ yctx,
                                            const unsigned long long* __restrict__ wacc,
                                            const float* __restrict__ Wf,
                                            float* __restrict__ fh2) {
  const int b = blockIdx.x;
  const int t = threadIdx.x;
  __shared__ float c_s[DIM];
  c_s[t] = (float)((double)(long long)yctx[(size_t)b * DIM + t] /
                   (double)(long long)wacc[b * HEADS + (t >> 5)]);
  __syncthreads();
  float a2 = 0.f;
  #pragma unroll 8
  for (int k = 0; k < DIM; ++k)
    a2 = fmaf(c_s[k], Wf[(size_t)k * DIM + t], a2);
  fh2[b * DIM + t] = a2;
}

// ---------------------------------------------------------------------------
// K3: fused LayerNorm + attn outer-sum, 2 rows per block (shared msr read).
// ---------------------------------------------------------------------------
__global__ __launch_bounds__(256) void k_ln_attn(const float* __restrict__ h,
                                                 const float* __restrict__ fh2,
                                                 const float* __restrict__ g,
                                                 const float* __restrict__ bb,
                                                 const float* __restrict__ msl,
                                                 const float* __restrict__ msr,
                                                 float* __restrict__ out,
                                                 float* __restrict__ attn) {
  const int row0 = blockIdx.x * 2;
  const int b = row0 >> 12;
  const int t = threadIdx.x;

  const float fh = fh2[b * DIM + t];
  const float x0 = h[(size_t)row0 * DIM + t] + fh;
  const float x1 = h[(size_t)(row0 + 1) * DIM + t] + fh;
  float s10 = x0, s20 = x0 * x0, s11 = x1, s21 = x1 * x1;
  #pragma unroll
  for (int o = 32; o > 0; o >>= 1) {
    s10 += __shfl_xor(s10, o, 64);
    s20 += __shfl_xor(s20, o, 64);
    s11 += __shfl_xor(s11, o, 64);
    s21 += __shfl_xor(s21, o, 64);
  }
  __shared__ float r1[2][4], r2[2][4];
  if ((t & 63) == 0) {
    r1[0][t >> 6] = s10; r2[0][t >> 6] = s20;
    r1[1][t >> 6] = s11; r2[1][t >> 6] = s21;
  }
  __syncthreads();
  const float gs = g[t], bs = bb[t];
  {
    const float s1 = r1[0][0] + r1[0][1] + r1[0][2] + r1[0][3];
    const float s2 = r2[0][0] + r2[0][1] + r2[0][2] + r2[0][3];
    const float mu = s1 * (1.f / 256.f);
    const float var = s2 * (1.f / 256.f) - mu * mu;
    const float rs = rsqrtf(var + 1e-5f);
    out[(size_t)row0 * DIM + t] = (x0 - mu) * rs * gs + bs;
  }
  {
    const float s1 = r1[1][0] + r1[1][1] + r1[1][2] + r1[1][3];
    const float s2 = r2[1][0] + r2[1][1] + r2[1][2] + r2[1][3];
    const float mu = s1 * (1.f / 256.f);
    const float var = s2 * (1.f / 256.f) - mu * mu;
    const float rs = rsqrtf(var + 1e-5f);
    out[(size_t)(row0 + 1) * DIM + t] = (x1 - mu) * rs * gs + bs;
  }

  // attn row-pair: attn[b,i,j] = msl[b,i] + msr[b,j]; msr read once
  const float v0 = msl[row0];
  const float v1 = msl[row0 + 1];
  const f32x4* mr4 = (const f32x4*)(msr + ((size_t)b << 12));
  f32x4* dst0 = (f32x4*)(attn + ((size_t)row0 << 12));
  f32x4* dst1 = (f32x4*)(attn + ((size_t)(row0 + 1) << 12));
  #pragma unroll
  for (int q = 0; q < 4; ++q) {
    const f32x4 m4 = mr4[q * 256 + t];
    __builtin_nontemporal_store(m4 + v0, &dst0[q * 256 + t]);
    __builtin_nontemporal_store(m4 + v1, &dst1[q * 256 + t]);
  }
}

// ---------------------------------------------------------------------------
extern "C" void kernel_launch(void* const* d_in, const int* in_sizes, int n_in,
                              void* d_out, int out_size, void* d_ws, size_t ws_size,
                              hipStream_t stream) {
  const float* h  = (const float*)d_in[0];
  const float* Wl = (const float*)d_in[1];
  const float* Wr = (const float*)d_in[2];
  const float* al = (const float*)d_in[3];
  const float* ar = (const float*)d_in[4];
  const float* Wf = (const float*)d_in[5];
  const float* g  = (const float*)d_in[6];
  const float* bb = (const float*)d_in[7];
  float* out = (float*)d_out;

  unsigned long long* yctx = (unsigned long long*)d_ws;         // 512 i64
  unsigned long long* wacc = yctx + BATCH * DIM;                // 16 i64
  float* msl = (float*)(wacc + BATCH * HEADS);                  // 8,192 f32
  float* msr = msl + M_ROWS;                                    // 8,192
  float* fh2 = msr + M_ROWS;                                    // 512
  unsigned short* Wt = (unsigned short*)(fh2 + BATCH * DIM);    // 512*256 u16

  k_prep<<<dim3(8, 16), 256, 0, stream>>>(Wl, Wr, Wt, yctx, wacc);
  k_gemm_fused<<<256, 512, 0, stream>>>(h, Wt, al, ar, msl, msr, yctx, wacc);
  k_fh<<<BATCH, 256, 0, stream>>>(yctx, wacc, Wf, fh2);
  k_ln_attn<<<M_ROWS / 2, 256, 0, stream>>>(h, fh2, g, bb, msl, msr,
                                            out, out + (size_t)M_ROWS * DIM);
}